// Round 4
// baseline (496.488 us; speedup 1.0000x reference)
//
#include <hip/hip_runtime.h>
#include <hip/hip_bf16.h>

// Tucker conv, 2-kernel pipeline:
//   stageA (fp32 VALU GEMM): x[b,c,h,w] -> x1p[b,hp=h+1,w'=w+1,s] bf16,
//     s-innermost, halos zeroed by the kernel itself.
//   fusedBC (barrier-free MFMA): B-fragments are direct 16B global loads from
//     x1p (s-innermost => k-contiguous); 9-shift core GEMM -> wave-local LDS
//     transpose -> expand GEMM (o=256) + bias -> out.

typedef __attribute__((ext_vector_type(8))) short short8;
typedef __attribute__((ext_vector_type(4))) short short4v;
typedef __attribute__((ext_vector_type(4))) float f32x4;

#define B_    32
#define CIN_  256
#define H_    56
#define W_    56
#define HW_   3136
#define COUT_ 256
#define HP_   58
#define WP_   64

// workspace byte offsets (16B-aligned)
#define OFF_FIRSTW  0u          // bf16 [64][256]         32768 B (unused by stageA now, kept)
#define OFF_COREW   32768u      // bf16 [9][64][64]       73728 B
#define OFF_LASTW   106496u     // bf16 [256][64]         32768 B
#define OFF_FIRSTTF 139264u     // fp32 [256 c][64 s]     65536 B
#define OFF_X1P     204800u     // bf16 [32][58][64][64]  15204352 B + 1KB slack
#define X1P_BYTES   15204352u

__device__ __forceinline__ unsigned short f2bf(float f) {
  union { float f; unsigned int u; } v; v.f = f;
  return (unsigned short)((v.u + 0x7FFFu + ((v.u >> 16) & 1u)) >> 16);
}
__device__ __forceinline__ short4v pack4(f32x4 a) {
  short4v p;
  p.x = (short)f2bf(a.x); p.y = (short)f2bf(a.y);
  p.z = (short)f2bf(a.z); p.w = (short)f2bf(a.w);
  return p;
}

// ---- prep: bf16 tables for BC + fp32 transposed first for stageA ----
__global__ __launch_bounds__(256) void prep_kernel(
    const float* __restrict__ first,   // [64][256]
    const float* __restrict__ core,    // [64][64][3][3]
    const float* __restrict__ last,    // [256][64]
    char* __restrict__ wsb) {
  int i = blockIdx.x * 256 + threadIdx.x;   // 86016 threads
  unsigned short* ws16 = (unsigned short*)wsb;
  if (i < 16384) {
    ws16[(OFF_FIRSTW >> 1) + i] = f2bf(first[i]);
  } else if (i < 53248) {
    int j = i - 16384;                       // coreW[t][r][s]
    int t = j >> 12, r = (j >> 6) & 63, s = j & 63;
    ws16[(OFF_COREW >> 1) + j] = f2bf(core[(r * 64 + s) * 9 + t]);
  } else if (i < 69632) {
    int j = i - 53248;
    ws16[(OFF_LASTW >> 1) + j] = f2bf(last[j]);   // [o][r]
  } else {
    int j = i - 69632;                       // firstTf[c][s] fp32
    int c = j >> 6, s = j & 63;
    ((float*)(wsb + OFF_FIRSTTF))[j] = first[s * CIN_ + c];
  }
}

// ---- stage A: fp32 VALU GEMM, one block per (b, hp) padded row ----
__global__ __launch_bounds__(256) void stageA_kernel(
    const float* __restrict__ x,
    char* __restrict__ wsb) {
  __shared__ float xt[64 * 64];   // 16 KB: [c-chunk 64][w 64]
  unsigned short* x1p = (unsigned short*)(wsb + OFF_X1P);
  const float* firstTf = (const float*)(wsb + OFF_FIRSTTF);

  int tid = threadIdx.x;
  int bid = blockIdx.x;                  // 32*58
  int b = bid / HP_, hp = bid - b * HP_;
  size_t rowbase = (size_t)(b * HP_ + hp) * (WP_ * 64);
  short8 z8 = {0,0,0,0,0,0,0,0};

  if (hp == 0 || hp == HP_ - 1) {        // halo rows: zeros (4096 halfs)
    *(short8*)(x1p + rowbase + tid * 16) = z8;
    *(short8*)(x1p + rowbase + tid * 16 + 8) = z8;
    return;
  }
  // zero halo cols w'=0 and 57..63 of this row
  if (tid < 64) {
    int c8 = tid >> 3;
    int col = (c8 == 0) ? 0 : (56 + c8);
    *(short8*)(x1p + rowbase + col * 64 + (tid & 7) * 8) = z8;
  }

  int h = hp - 1;
  const float* xrow = x + (size_t)b * (CIN_ * HW_) + h * W_;
  int w  = tid & 63;
  int sq = __builtin_amdgcn_readfirstlane(tid >> 6);   // wave id = s-quarter
  int cr   = tid >> 2;                   // 0..63: c within chunk
  int part = tid & 3;

  float acc[16];
#pragma unroll
  for (int j = 0; j < 16; ++j) acc[j] = 0.f;

  for (int c0 = 0; c0 < CIN_; c0 += 64) {
    const float* p = xrow + (size_t)(c0 + cr) * HW_;
    float4 v0 = *(const float4*)(p + part * 4);
    float4 v1 = *(const float4*)(p + (part + 4) * 4);
    float4 v2 = *(const float4*)(p + (part + 8) * 4);
    *(float4*)&xt[cr * 64 + part * 4] = v0;
    *(float4*)&xt[cr * 64 + (part + 4) * 4] = v1;
    *(float4*)&xt[cr * 64 + (part + 8) * 4] = v2;
    if (part < 2)
      *(float4*)&xt[cr * 64 + (part + 12) * 4] = *(const float4*)(p + (part + 12) * 4);
    __syncthreads();

    const float* ft = firstTf + (size_t)c0 * 64 + sq * 16;
#pragma unroll 8
    for (int cc = 0; cc < 64; ++cc) {
      float xv = xt[cc * 64 + w];
      f32x4 f0 = *(const f32x4*)(ft + cc * 64 + 0);
      f32x4 f1 = *(const f32x4*)(ft + cc * 64 + 4);
      f32x4 f2 = *(const f32x4*)(ft + cc * 64 + 8);
      f32x4 f3 = *(const f32x4*)(ft + cc * 64 + 12);
      acc[0]  += f0.x * xv; acc[1]  += f0.y * xv; acc[2]  += f0.z * xv; acc[3]  += f0.w * xv;
      acc[4]  += f1.x * xv; acc[5]  += f1.y * xv; acc[6]  += f1.z * xv; acc[7]  += f1.w * xv;
      acc[8]  += f2.x * xv; acc[9]  += f2.y * xv; acc[10] += f2.z * xv; acc[11] += f2.w * xv;
      acc[12] += f3.x * xv; acc[13] += f3.y * xv; acc[14] += f3.z * xv; acc[15] += f3.w * xv;
    }
    __syncthreads();
  }

  if (w < W_) {                          // w' = w+1 in 1..56
    unsigned short* o = x1p + rowbase + (size_t)(w + 1) * 64 + sq * 16;
    short8 lo, hi;
#pragma unroll
    for (int j = 0; j < 8; ++j) { lo[j] = (short)f2bf(acc[j]); hi[j] = (short)f2bf(acc[8 + j]); }
    *(short8*)o = lo;
    *(short8*)(o + 8) = hi;
  }
}

// ---- fused B+C: barrier-free; one block per (b, h), wave per 16-w chunk ----
__global__ __launch_bounds__(256) void fusedBC_kernel(
    const char* __restrict__ wsb,
    const float* __restrict__ bias,
    float* __restrict__ out) {
  __shared__ unsigned short yt[64 * 72];   // 9216 B: [w 64][r 64 + 8 pad]
  const unsigned short* coreW = (const unsigned short*)(wsb + OFF_COREW);
  const unsigned short* lastW = (const unsigned short*)(wsb + OFF_LASTW);
  const unsigned short* x1p   = (const unsigned short*)(wsb + OFF_X1P);

  int tid = threadIdx.x, wave = tid >> 6, lane = tid & 63;
  int quad = lane >> 4, l15 = lane & 15;
  int bid = blockIdx.x;                  // 32*56
  int b = bid / H_, h = bid - b * H_;
  int w = wave * 16 + l15;               // 0..63 (>=56 masked at store)

  const unsigned short* xbase = x1p + (size_t)(b * HP_ + h) * (WP_ * 64);

  // ---- B-phase: y1[r=64][w]; bfrags are direct 16B global loads (s-innermost)
  f32x4 acc[4] = {{0,0,0,0},{0,0,0,0},{0,0,0,0},{0,0,0,0}};
#pragma unroll
  for (int kh = 0; kh < 3; ++kh) {
#pragma unroll
    for (int kw = 0; kw < 3; ++kw) {
      int t = kh * 3 + kw;
      const unsigned short* xs = xbase + (size_t)(kh * WP_ + w + kw) * 64;
#pragma unroll
      for (int k0 = 0; k0 < 64; k0 += 32) {
        short8 bfrag = *(const short8*)(xs + k0 + quad * 8);
#pragma unroll
        for (int mt = 0; mt < 4; ++mt) {
          short8 af = *(const short8*)(coreW + (t * 64 + mt * 16 + l15) * 64 + k0 + quad * 8);
          acc[mt] = __builtin_amdgcn_mfma_f32_16x16x32_bf16(af, bfrag, acc[mt], 0, 0, 0);
        }
      }
    }
  }

  // ---- wave-local transpose: yt[w][r] (each wave touches only its own w)
  unsigned short* ytw = &yt[w * 72];
#pragma unroll
  for (int mt = 0; mt < 4; ++mt)
    *(short4v*)(ytw + mt * 16 + quad * 4) = pack4(acc[mt]);

  // ---- C-phase: out[o=256][w] in two o-halves (VGPR cap)
  float* ob = out + (size_t)b * (COUT_ * HW_) + h * W_ + w;
#pragma unroll
  for (int half = 0; half < 2; ++half) {
    f32x4 acc2[8];
#pragma unroll
    for (int mt = 0; mt < 8; ++mt) acc2[mt] = (f32x4){0, 0, 0, 0};
#pragma unroll
    for (int k0 = 0; k0 < 64; k0 += 32) {
      short8 bfragC = *(const short8*)(ytw + k0 + quad * 8);
#pragma unroll
      for (int mt = 0; mt < 8; ++mt) {
        short8 af = *(const short8*)(lastW + ((half * 8 + mt) * 16 + l15) * 64 + k0 + quad * 8);
        acc2[mt] = __builtin_amdgcn_mfma_f32_16x16x32_bf16(af, bfragC, acc2[mt], 0, 0, 0);
      }
    }
    if (w < W_) {
#pragma unroll
      for (int mt = 0; mt < 8; ++mt) {
        int o = (half * 8 + mt) * 16 + quad * 4;
        float4 bv = *(const float4*)(bias + o);
        ob[(size_t)(o + 0) * HW_] = acc2[mt].x + bv.x;
        ob[(size_t)(o + 1) * HW_] = acc2[mt].y + bv.y;
        ob[(size_t)(o + 2) * HW_] = acc2[mt].z + bv.z;
        ob[(size_t)(o + 3) * HW_] = acc2[mt].w + bv.w;
      }
    }
  }
}

extern "C" void kernel_launch(void* const* d_in, const int* in_sizes, int n_in,
                              void* d_out, int out_size, void* d_ws, size_t ws_size,
                              hipStream_t stream) {
  const float* x     = (const float*)d_in[0];
  const float* first = (const float*)d_in[1];
  const float* core  = (const float*)d_in[2];
  const float* last  = (const float*)d_in[3];
  const float* bias  = (const float*)d_in[4];
  float* out = (float*)d_out;
  char* wsb  = (char*)d_ws;

  prep_kernel<<<336, 256, 0, stream>>>(first, core, last, wsb);
  stageA_kernel<<<B_ * HP_, 256, 0, stream>>>(x, wsb);
  fusedBC_kernel<<<B_ * H_, 256, 0, stream>>>(wsb, bias, out);
}